// Round 7
// baseline (2506.166 us; speedup 1.0000x reference)
//
#include <hip/hip_runtime.h>
#include <hip/hip_bf16.h>
#include <stdint.h>

#define VOCAB 32000
#define HIDDEN 512
#define TSEQ 1024
#define NWAVE 32           // 32 single-wave WGs x 16 rows = 512
#define SENT 0x7F807F80u   // two +inf bf16 — unrepresentable in tanh/h0 data

typedef __attribute__((ext_vector_type(4))) float f32x4;
typedef __attribute__((ext_vector_type(8))) short short8;
typedef __attribute__((ext_vector_type(2))) unsigned uint2v;

union bfpack8 { short8 s; __hip_bfloat16 e[8]; };
union frag_u { short8 s; uint4 u; };

// ---------------- kernel: fill h rows 1..TSEQ with the sentinel ----------------
__global__ __launch_bounds__(256) void k_fill(uint4* __restrict__ p, int n4) {
  const int i = blockIdx.x * blockDim.x + threadIdx.x;
  if (i < n4) {
    uint4 v; v.x = SENT; v.y = SENT; v.z = SENT; v.w = SENT;
    p[i] = v;
  }
}

// ---------------- kernel: f32 -> bf16 convert (Why_w) ----------------
__global__ __launch_bounds__(256) void k_convert(const float* __restrict__ in,
                                                 __hip_bfloat16* __restrict__ out,
                                                 int n4) {
  int stride = gridDim.x * blockDim.x;
  for (int i = blockIdx.x * blockDim.x + threadIdx.x; i < n4; i += stride) {
    const float4 v = *reinterpret_cast<const float4*>(in + (size_t)i * 4);
    union { __hip_bfloat16 h[4]; ushort4 u; } p;
    p.h[0] = __float2bfloat16(v.x);
    p.h[1] = __float2bfloat16(v.y);
    p.h[2] = __float2bfloat16(v.z);
    p.h[3] = __float2bfloat16(v.w);
    *reinterpret_cast<ushort4*>(out + (size_t)i * 4) = p.u;
  }
}

// ---- pre[t][j] = Wxh_w[j][idx[t]] + Wxh_b[j] + Whh_b[j];  h_bf[0] = bf16(h0) ----
__global__ __launch_bounds__(512) void k_pre(const int* __restrict__ idx,
                                             const float* __restrict__ h0,
                                             const float* __restrict__ Wxh_w,
                                             const float* __restrict__ Wxh_b,
                                             const float* __restrict__ Whh_b,
                                             float* __restrict__ pre,
                                             __hip_bfloat16* __restrict__ h_bf) {
  const int t = blockIdx.x;
  const int j = threadIdx.x;
  const int c = idx[t];
  pre[(size_t)t * HIDDEN + j] = Wxh_w[(size_t)j * VOCAB + c] + Wxh_b[j] + Whh_b[j];
  if (t == 0) h_bf[j] = __float2bfloat16(h0[j]);  // finite (h0 ~ N(0,1)) => never SENT
}

// ---------------- kernel: sequential scan — 32 independent waves ----------------
// Wave w owns rows [16w,16w+16). Whh fragments (hi+lo bf16 split) live in LDS
// (32 KB, prepped once) — ends the VGPR-residency fight (R2/R6 regressions).
// Cross-wave handoff: sentinel-in-data. Producers fire-and-forget sc0 sc1
// stores of h (bf16, finite => never SENT); consumers bulk-load the row until
// every dword != SENT. Each dword comes entirely from one 8B store => no torn
// reads. One coherent-point RTT per poll; no flags, no store-ack, no fences.
// Deadlock-free: producers never wait; step t needs only step t-1 data.
__global__ __launch_bounds__(64, 1) void k_scan(const float* __restrict__ pre,
                                                const float* __restrict__ Whh,
                                                __hip_bfloat16* __restrict__ h_bf,
                                                float* __restrict__ h_final) {
  __shared__ short8 afrag[32][64];  // [2*kk + (hi:0,lo:1)][lane], 32 KB

  const int wv = blockIdx.x;   // 0..31
  const int l = threadIdx.x;   // 0..63
  const int l15 = l & 15;
  const int l4 = l >> 4;
  const int base = wv * 16;

  // one-time: build A-fragments (W ~= hi(bf16) + lo(bf16)), stash in LDS
  {
    const float* wp = Whh + (size_t)(base + l15) * HIDDEN + l4 * 8;
#pragma unroll
    for (int kk = 0; kk < 16; ++kk) {
      const f32x4 a = *reinterpret_cast<const f32x4*>(wp + kk * 32);
      const f32x4 b = *reinterpret_cast<const f32x4*>(wp + kk * 32 + 4);
      bfpack8 hi, lo;
#pragma unroll
      for (int i = 0; i < 4; ++i) {
        hi.e[i] = __float2bfloat16(a[i]);
        lo.e[i] = __float2bfloat16(a[i] - __bfloat162float(hi.e[i]));
        hi.e[4 + i] = __float2bfloat16(b[i]);
        lo.e[4 + i] = __float2bfloat16(b[i] - __bfloat162float(hi.e[4 + i]));
      }
      afrag[2 * kk][l] = hi.s;
      afrag[2 * kk + 1][l] = lo.s;
    }
  }
  // single wave per WG: LDS writes/reads are same-wave; compiler inserts lgkmcnt

  for (int t = 1; t <= TSEQ; ++t) {
    // additive term (read-only input, cached, independent of h)
    const float* pp = pre + (size_t)(t - 1) * HIDDEN + base + l4 * 4;
    const f32x4 pv = *reinterpret_cast<const f32x4*>(pp);

    // poll+load h row t-1: repeat bulk load until no dword is the sentinel.
    // lane l reads 16B at byte offset kk*64 + l4*16.
    const __hip_bfloat16* hbase = h_bf + (size_t)(t - 1) * HIDDEN + l4 * 8;
    short8 bq[16];
    unsigned ok;
    do {
      asm volatile(
          "global_load_dwordx4 %0, %16, off sc0 sc1\n\t"
          "global_load_dwordx4 %1, %16, off offset:64 sc0 sc1\n\t"
          "global_load_dwordx4 %2, %16, off offset:128 sc0 sc1\n\t"
          "global_load_dwordx4 %3, %16, off offset:192 sc0 sc1\n\t"
          "global_load_dwordx4 %4, %16, off offset:256 sc0 sc1\n\t"
          "global_load_dwordx4 %5, %16, off offset:320 sc0 sc1\n\t"
          "global_load_dwordx4 %6, %16, off offset:384 sc0 sc1\n\t"
          "global_load_dwordx4 %7, %16, off offset:448 sc0 sc1\n\t"
          "global_load_dwordx4 %8, %16, off offset:512 sc0 sc1\n\t"
          "global_load_dwordx4 %9, %16, off offset:576 sc0 sc1\n\t"
          "global_load_dwordx4 %10, %16, off offset:640 sc0 sc1\n\t"
          "global_load_dwordx4 %11, %16, off offset:704 sc0 sc1\n\t"
          "global_load_dwordx4 %12, %16, off offset:768 sc0 sc1\n\t"
          "global_load_dwordx4 %13, %16, off offset:832 sc0 sc1\n\t"
          "global_load_dwordx4 %14, %16, off offset:896 sc0 sc1\n\t"
          "global_load_dwordx4 %15, %16, off offset:960 sc0 sc1\n\t"
          "s_waitcnt vmcnt(0)"
          : "=&v"(bq[0]), "=&v"(bq[1]), "=&v"(bq[2]), "=&v"(bq[3]),
            "=&v"(bq[4]), "=&v"(bq[5]), "=&v"(bq[6]), "=&v"(bq[7]),
            "=&v"(bq[8]), "=&v"(bq[9]), "=&v"(bq[10]), "=&v"(bq[11]),
            "=&v"(bq[12]), "=&v"(bq[13]), "=&v"(bq[14]), "=&v"(bq[15])
          : "v"(hbase)
          : "memory");
      ok = 1u;
#pragma unroll
      for (int kk = 0; kk < 16; ++kk) {
        frag_u f; f.s = bq[kk];
        ok &= (unsigned)(f.u.x != SENT) & (unsigned)(f.u.y != SENT) &
              (unsigned)(f.u.z != SENT) & (unsigned)(f.u.w != SENT);
      }
    } while (!__all(ok != 0u));

    // 4 independent accumulator chains; A fragments streamed from LDS
    f32x4 acc0 = {0.f, 0.f, 0.f, 0.f};
    f32x4 acc1 = {0.f, 0.f, 0.f, 0.f};
    f32x4 acc2 = {0.f, 0.f, 0.f, 0.f};
    f32x4 acc3 = {0.f, 0.f, 0.f, 0.f};
#pragma unroll
    for (int kk = 0; kk < 8; ++kk) {
      acc0 = __builtin_amdgcn_mfma_f32_16x16x32_bf16(afrag[2 * kk][l], bq[kk], acc0, 0, 0, 0);
      acc2 = __builtin_amdgcn_mfma_f32_16x16x32_bf16(afrag[2 * kk + 1][l], bq[kk], acc2, 0, 0, 0);
      acc1 = __builtin_amdgcn_mfma_f32_16x16x32_bf16(afrag[2 * (kk + 8)][l], bq[kk + 8], acc1, 0, 0, 0);
      acc3 = __builtin_amdgcn_mfma_f32_16x16x32_bf16(afrag[2 * (kk + 8) + 1][l], bq[kk + 8], acc3, 0, 0, 0);
    }
    const f32x4 acc = (acc0 + acc1) + (acc2 + acc3);

    // h_new = tanh(pre + acc); lanes compute rows base + l4*4 + q (cols redundant)
    float y[4];
#pragma unroll
    for (int q = 0; q < 4; ++q) {
      const float x = fminf(fmaxf(pv[q] + acc[q], -15.f), 15.f);
      const float e = __expf(2.f * x);
      y[q] = (e - 1.f) * __builtin_amdgcn_rcpf(e + 1.f);
    }

    if (l15 == 0) {  // lanes l4=0..3 publish rows base + l4*4 + q (8B each)
      union { uint2v u; __hip_bfloat16 e[4]; } pk;
#pragma unroll
      for (int q = 0; q < 4; ++q) pk.e[q] = __float2bfloat16(y[q]);
      __hip_bfloat16* ha = h_bf + (size_t)t * HIDDEN + base + l4 * 4;
      asm volatile("global_store_dwordx2 %0, %1, off sc0 sc1"
                   :: "v"(ha), "v"(pk.u) : "memory");  // fire and forget
      if (t == TSEQ) {
        f32x4 f = {y[0], y[1], y[2], y[3]};
        *reinterpret_cast<f32x4*>(h_final + base + l4 * 4) = f;
      }
    }
  }
}

// ---------------- kernel: logits = h_seq @ Why_w^T + bias (bf16 MFMA) ----------------
__global__ __launch_bounds__(256) void k_gemm(const __hip_bfloat16* __restrict__ A,
                                              const __hip_bfloat16* __restrict__ B,
                                              const float* __restrict__ bias,
                                              float* __restrict__ C) {
  __shared__ __hip_bfloat16 As[128][32];
  __shared__ __hip_bfloat16 Bs[128][32];
  const int bn = blockIdx.x;  // 0..249
  const int bm = blockIdx.y;  // 0..7
  const int tid = threadIdx.x;
  const int lane = tid & 63;
  const int wid = tid >> 6;
  const int wr = (wid >> 1) * 64;
  const int wc = (wid & 1) * 64;
  const int l15 = lane & 15;
  const int kc = lane >> 4;

  const int sr = tid >> 1;        // staging row 0..127
  const int sc = (tid & 1) * 16;  // staging k offset {0,16}

  const __hip_bfloat16* Ag = A + (size_t)(bm * 128 + sr) * HIDDEN + sc;
  const __hip_bfloat16* Bg = B + (size_t)(bn * 128 + sr) * HIDDEN + sc;

  f32x4 acc[4][4];
#pragma unroll
  for (int m = 0; m < 4; ++m)
#pragma unroll
    for (int n = 0; n < 4; ++n) {
      acc[m][n][0] = 0.f; acc[m][n][1] = 0.f; acc[m][n][2] = 0.f; acc[m][n][3] = 0.f;
    }

  for (int ks = 0; ks < HIDDEN; ks += 32) {
    __syncthreads();  // WAR: previous iteration's reads done
    *reinterpret_cast<short8*>(&As[sr][sc])     = *reinterpret_cast<const short8*>(Ag + ks);
    *reinterpret_cast<short8*>(&As[sr][sc + 8]) = *reinterpret_cast<const short8*>(Ag + ks + 8);
    *reinterpret_cast<short8*>(&Bs[sr][sc])     = *reinterpret_cast<const short8*>(Bg + ks);
    *reinterpret_cast<short8*>(&Bs[sr][sc + 8]) = *reinterpret_cast<const short8*>(Bg + ks + 8);
    __syncthreads();

    short8 af[4], bfr[4];
#pragma unroll
    for (int m = 0; m < 4; ++m)
      af[m] = *reinterpret_cast<const short8*>(&As[wr + m * 16 + l15][kc * 8]);
#pragma unroll
    for (int n = 0; n < 4; ++n)
      bfr[n] = *reinterpret_cast<const short8*>(&Bs[wc + n * 16 + l15][kc * 8]);
#pragma unroll
    for (int m = 0; m < 4; ++m)
#pragma unroll
      for (int n = 0; n < 4; ++n)
        acc[m][n] = __builtin_amdgcn_mfma_f32_16x16x32_bf16(af[m], bfr[n], acc[m][n], 0, 0, 0);
  }

  // epilogue: C/D layout col = lane&15, row = (lane>>4)*4 + q
#pragma unroll
  for (int m = 0; m < 4; ++m) {
#pragma unroll
    for (int n = 0; n < 4; ++n) {
      const int vcol = bn * 128 + wc + n * 16 + l15;
      const float bv = bias[vcol];
#pragma unroll
      for (int q = 0; q < 4; ++q) {
        const int trow = bm * 128 + wr + m * 16 + kc * 4 + q;
        C[(size_t)trow * VOCAB + vcol] = acc[m][n][q] + bv;
      }
    }
  }
}

extern "C" void kernel_launch(void* const* d_in, const int* in_sizes, int n_in,
                              void* d_out, int out_size, void* d_ws, size_t ws_size,
                              hipStream_t stream) {
  (void)in_sizes; (void)n_in; (void)out_size; (void)ws_size;

  const int*   idx   = (const int*)d_in[0];
  const float* h0    = (const float*)d_in[1];
  const float* Wxh_w = (const float*)d_in[2];
  const float* Wxh_b = (const float*)d_in[3];
  const float* Whh_w = (const float*)d_in[4];
  const float* Whh_b = (const float*)d_in[5];
  const float* Why_w = (const float*)d_in[6];
  const float* Why_b = (const float*)d_in[7];
  float* out = (float*)d_out;

  // workspace layout (bytes)
  char* ws = (char*)d_ws;
  __hip_bfloat16* why_bf = (__hip_bfloat16*)(ws);                      // 32,768,000
  float* pre = (float*)(ws + 32768000);                                // 2,097,152
  __hip_bfloat16* h_bf = (__hip_bfloat16*)(ws + 32768000 + 2097152);   // (TSEQ+1)*512*2 = 1,049,600

  // sentinel-fill h rows 1..TSEQ (replay-safe: refilled every call)
  k_fill<<<(TSEQ * HIDDEN / 8 + 255) / 256, 256, 0, stream>>>(
      (uint4*)(h_bf + HIDDEN), TSEQ * HIDDEN / 8);
  k_convert<<<2048, 256, 0, stream>>>(Why_w, why_bf, (VOCAB * HIDDEN) / 4);
  k_pre<<<TSEQ, HIDDEN, 0, stream>>>(idx, h0, Wxh_w, Wxh_b, Whh_b, pre, h_bf);
  k_scan<<<NWAVE, 64, 0, stream>>>(pre, Whh_w, h_bf, out + 32768000);
  k_gemm<<<dim3(VOCAB / 128, TSEQ / 128), 256, 0, stream>>>(h_bf + HIDDEN, why_bf, Why_b, out);
}

// Round 8
// 1516.460 us; speedup vs baseline: 1.6526x; 1.6526x over previous
//
#include <hip/hip_runtime.h>
#include <hip/hip_bf16.h>
#include <stdint.h>

#define VOCAB 32000
#define HIDDEN 512
#define TSEQ 1024
#define NWAVE 32           // 32 single-wave WGs x 16 rows = 512
#define SENT 0x7F807F80u   // two +inf bf16 — unrepresentable in tanh/h0 data

typedef __attribute__((ext_vector_type(4))) float f32x4;
typedef __attribute__((ext_vector_type(8))) short short8;
typedef __attribute__((ext_vector_type(2))) unsigned uint2v;

union bfpack8 { short8 s; __hip_bfloat16 e[8]; };
union frag_u { short8 s; uint4 u; };

// ---------------- kernel: fill h rows 1..TSEQ with the sentinel ----------------
__global__ __launch_bounds__(256) void k_fill(uint4* __restrict__ p, int n4) {
  const int i = blockIdx.x * blockDim.x + threadIdx.x;
  if (i < n4) {
    uint4 v; v.x = SENT; v.y = SENT; v.z = SENT; v.w = SENT;
    p[i] = v;
  }
}

// ---------------- kernel: f32 -> bf16 convert (Why_w) ----------------
__global__ __launch_bounds__(256) void k_convert(const float* __restrict__ in,
                                                 __hip_bfloat16* __restrict__ out,
                                                 int n4) {
  int stride = gridDim.x * blockDim.x;
  for (int i = blockIdx.x * blockDim.x + threadIdx.x; i < n4; i += stride) {
    const float4 v = *reinterpret_cast<const float4*>(in + (size_t)i * 4);
    union { __hip_bfloat16 h[4]; ushort4 u; } p;
    p.h[0] = __float2bfloat16(v.x);
    p.h[1] = __float2bfloat16(v.y);
    p.h[2] = __float2bfloat16(v.z);
    p.h[3] = __float2bfloat16(v.w);
    *reinterpret_cast<ushort4*>(out + (size_t)i * 4) = p.u;
  }
}

// ---- pre[t][j] = Wxh_w[j][idx[t]] + Wxh_b[j] + Whh_b[j];  h_bf[0] = bf16(h0) ----
__global__ __launch_bounds__(512) void k_pre(const int* __restrict__ idx,
                                             const float* __restrict__ h0,
                                             const float* __restrict__ Wxh_w,
                                             const float* __restrict__ Wxh_b,
                                             const float* __restrict__ Whh_b,
                                             float* __restrict__ pre,
                                             __hip_bfloat16* __restrict__ h_bf) {
  const int t = blockIdx.x;
  const int j = threadIdx.x;
  const int c = idx[t];
  pre[(size_t)t * HIDDEN + j] = Wxh_w[(size_t)j * VOCAB + c] + Wxh_b[j] + Whh_b[j];
  if (t == 0) h_bf[j] = __float2bfloat16(h0[j]);  // finite (h0 ~ N(0,1)) => never SENT
}

// ---------------- kernel: sequential scan — 32 independent waves ----------------
// Wave w owns rows [16w,16w+16). Whh fragments (hi+lo bf16 split) in LDS (32 KB).
// Cross-wave handoff: sentinel-in-data with PERFECTLY COALESCED bypass loads:
//   consumer: ONE global_load_dwordx4 sc0 sc1 (lane l -> distinct 16B of the row)
//             retried until no dword == SENT; then a 1KB LDS bounce redistributes
//             to MFMA B-fragment layout (1 ds_write_b128 + 16 broadcast reads).
//   producer: fire-and-forget sc0 sc1 stores (32B contiguous per wave, 1 line).
// Torn-proof: each dword comes entirely from one aligned 8B store.
// Deadlock-free: producers never wait; step t needs only step t-1 data.
__global__ __launch_bounds__(64, 1) void k_scan(const float* __restrict__ pre,
                                                const float* __restrict__ Whh,
                                                __hip_bfloat16* __restrict__ h_bf,
                                                float* __restrict__ h_final) {
  __shared__ short8 afrag[32][64];                      // 32 KB weight fragments
  __shared__ __align__(16) __hip_bfloat16 hstage[HIDDEN];  // 1 KB h bounce

  const int wv = blockIdx.x;   // 0..31
  const int l = threadIdx.x;   // 0..63
  const int l15 = l & 15;
  const int l4 = l >> 4;
  const int base = wv * 16;

  // one-time: build A-fragments (W ~= hi(bf16) + lo(bf16)), stash in LDS
  {
    const float* wp = Whh + (size_t)(base + l15) * HIDDEN + l4 * 8;
#pragma unroll
    for (int kk = 0; kk < 16; ++kk) {
      const f32x4 a = *reinterpret_cast<const f32x4*>(wp + kk * 32);
      const f32x4 b = *reinterpret_cast<const f32x4*>(wp + kk * 32 + 4);
      bfpack8 hi, lo;
#pragma unroll
      for (int i = 0; i < 4; ++i) {
        hi.e[i] = __float2bfloat16(a[i]);
        lo.e[i] = __float2bfloat16(a[i] - __bfloat162float(hi.e[i]));
        hi.e[4 + i] = __float2bfloat16(b[i]);
        lo.e[4 + i] = __float2bfloat16(b[i] - __bfloat162float(hi.e[4 + i]));
      }
      afrag[2 * kk][l] = hi.s;
      afrag[2 * kk + 1][l] = lo.s;
    }
  }
  // single wave per WG: LDS producer==consumer wave; compiler orders via lgkmcnt

  for (int t = 1; t <= TSEQ; ++t) {
    // additive term (read-only input, cached, independent of h)
    const float* pp = pre + (size_t)(t - 1) * HIDDEN + base + l4 * 4;
    const f32x4 pv = *reinterpret_cast<const f32x4*>(pp);

    // ---- coalesced poll-load: lane l owns bytes [16l,16l+16) of row t-1 ----
    const __hip_bfloat16* hrow = h_bf + (size_t)(t - 1) * HIDDEN + l * 8;
    short8 hv;
    unsigned ok;
    do {
      asm volatile("global_load_dwordx4 %0, %1, off sc0 sc1\n\ts_waitcnt vmcnt(0)"
                   : "=&v"(hv) : "v"(hrow) : "memory");
      frag_u f; f.s = hv;
      ok = (unsigned)(f.u.x != SENT) & (unsigned)(f.u.y != SENT) &
           (unsigned)(f.u.z != SENT) & (unsigned)(f.u.w != SENT);
    } while (!__all(ok != 0u));

    // ---- LDS bounce: coalesced layout -> B-fragment layout ----
    *reinterpret_cast<short8*>(&hstage[l * 8]) = hv;  // ds_write_b128
    short8 bq[16];
#pragma unroll
    for (int kk = 0; kk < 16; ++kk)
      bq[kk] = *reinterpret_cast<const short8*>(&hstage[kk * 32 + l4 * 8]);

    // 4 independent accumulator chains; A fragments streamed from LDS
    f32x4 acc0 = {0.f, 0.f, 0.f, 0.f};
    f32x4 acc1 = {0.f, 0.f, 0.f, 0.f};
    f32x4 acc2 = {0.f, 0.f, 0.f, 0.f};
    f32x4 acc3 = {0.f, 0.f, 0.f, 0.f};
#pragma unroll
    for (int kk = 0; kk < 8; ++kk) {
      acc0 = __builtin_amdgcn_mfma_f32_16x16x32_bf16(afrag[2 * kk][l], bq[kk], acc0, 0, 0, 0);
      acc2 = __builtin_amdgcn_mfma_f32_16x16x32_bf16(afrag[2 * kk + 1][l], bq[kk], acc2, 0, 0, 0);
      acc1 = __builtin_amdgcn_mfma_f32_16x16x32_bf16(afrag[2 * (kk + 8)][l], bq[kk + 8], acc1, 0, 0, 0);
      acc3 = __builtin_amdgcn_mfma_f32_16x16x32_bf16(afrag[2 * (kk + 8) + 1][l], bq[kk + 8], acc3, 0, 0, 0);
    }
    const f32x4 acc = (acc0 + acc1) + (acc2 + acc3);

    // h_new = tanh(pre + acc); lanes compute rows base + l4*4 + q (cols redundant)
    float y[4];
#pragma unroll
    for (int q = 0; q < 4; ++q) {
      const float x = fminf(fmaxf(pv[q] + acc[q], -15.f), 15.f);
      const float e = __expf(2.f * x);
      y[q] = (e - 1.f) * __builtin_amdgcn_rcpf(e + 1.f);
    }

    if (l15 == 0) {  // lanes l4=0..3 publish rows base + l4*4 + q (8B each, 1 line/wave)
      union { uint2v u; __hip_bfloat16 e[4]; } pk;
#pragma unroll
      for (int q = 0; q < 4; ++q) pk.e[q] = __float2bfloat16(y[q]);
      __hip_bfloat16* ha = h_bf + (size_t)t * HIDDEN + base + l4 * 4;
      asm volatile("global_store_dwordx2 %0, %1, off sc0 sc1"
                   :: "v"(ha), "v"(pk.u) : "memory");  // fire and forget
      if (t == TSEQ) {
        f32x4 f = {y[0], y[1], y[2], y[3]};
        *reinterpret_cast<f32x4*>(h_final + base + l4 * 4) = f;
      }
    }
  }
}

// ---------------- kernel: logits = h_seq @ Why_w^T + bias (bf16 MFMA) ----------------
__global__ __launch_bounds__(256) void k_gemm(const __hip_bfloat16* __restrict__ A,
                                              const __hip_bfloat16* __restrict__ B,
                                              const float* __restrict__ bias,
                                              float* __restrict__ C) {
  __shared__ __hip_bfloat16 As[128][32];
  __shared__ __hip_bfloat16 Bs[128][32];
  const int bn = blockIdx.x;  // 0..249
  const int bm = blockIdx.y;  // 0..7
  const int tid = threadIdx.x;
  const int lane = tid & 63;
  const int wid = tid >> 6;
  const int wr = (wid >> 1) * 64;
  const int wc = (wid & 1) * 64;
  const int l15 = lane & 15;
  const int kc = lane >> 4;

  const int sr = tid >> 1;        // staging row 0..127
  const int sc = (tid & 1) * 16;  // staging k offset {0,16}

  const __hip_bfloat16* Ag = A + (size_t)(bm * 128 + sr) * HIDDEN + sc;
  const __hip_bfloat16* Bg = B + (size_t)(bn * 128 + sr) * HIDDEN + sc;

  f32x4 acc[4][4];
#pragma unroll
  for (int m = 0; m < 4; ++m)
#pragma unroll
    for (int n = 0; n < 4; ++n) {
      acc[m][n][0] = 0.f; acc[m][n][1] = 0.f; acc[m][n][2] = 0.f; acc[m][n][3] = 0.f;
    }

  for (int ks = 0; ks < HIDDEN; ks += 32) {
    __syncthreads();  // WAR: previous iteration's reads done
    *reinterpret_cast<short8*>(&As[sr][sc])     = *reinterpret_cast<const short8*>(Ag + ks);
    *reinterpret_cast<short8*>(&As[sr][sc + 8]) = *reinterpret_cast<const short8*>(Ag + ks + 8);
    *reinterpret_cast<short8*>(&Bs[sr][sc])     = *reinterpret_cast<const short8*>(Bg + ks);
    *reinterpret_cast<short8*>(&Bs[sr][sc + 8]) = *reinterpret_cast<const short8*>(Bg + ks + 8);
    __syncthreads();

    short8 af[4], bfr[4];
#pragma unroll
    for (int m = 0; m < 4; ++m)
      af[m] = *reinterpret_cast<const short8*>(&As[wr + m * 16 + l15][kc * 8]);
#pragma unroll
    for (int n = 0; n < 4; ++n)
      bfr[n] = *reinterpret_cast<const short8*>(&Bs[wc + n * 16 + l15][kc * 8]);
#pragma unroll
    for (int m = 0; m < 4; ++m)
#pragma unroll
      for (int n = 0; n < 4; ++n)
        acc[m][n] = __builtin_amdgcn_mfma_f32_16x16x32_bf16(af[m], bfr[n], acc[m][n], 0, 0, 0);
  }

  // epilogue: C/D layout col = lane&15, row = (lane>>4)*4 + q
#pragma unroll
  for (int m = 0; m < 4; ++m) {
#pragma unroll
    for (int n = 0; n < 4; ++n) {
      const int vcol = bn * 128 + wc + n * 16 + l15;
      const float bv = bias[vcol];
#pragma unroll
      for (int q = 0; q < 4; ++q) {
        const int trow = bm * 128 + wr + m * 16 + kc * 4 + q;
        C[(size_t)trow * VOCAB + vcol] = acc[m][n][q] + bv;
      }
    }
  }
}

extern "C" void kernel_launch(void* const* d_in, const int* in_sizes, int n_in,
                              void* d_out, int out_size, void* d_ws, size_t ws_size,
                              hipStream_t stream) {
  (void)in_sizes; (void)n_in; (void)out_size; (void)ws_size;

  const int*   idx   = (const int*)d_in[0];
  const float* h0    = (const float*)d_in[1];
  const float* Wxh_w = (const float*)d_in[2];
  const float* Wxh_b = (const float*)d_in[3];
  const float* Whh_w = (const float*)d_in[4];
  const float* Whh_b = (const float*)d_in[5];
  const float* Why_w = (const float*)d_in[6];
  const float* Why_b = (const float*)d_in[7];
  float* out = (float*)d_out;

  // workspace layout (bytes)
  char* ws = (char*)d_ws;
  __hip_bfloat16* why_bf = (__hip_bfloat16*)(ws);                      // 32,768,000
  float* pre = (float*)(ws + 32768000);                                // 2,097,152
  __hip_bfloat16* h_bf = (__hip_bfloat16*)(ws + 32768000 + 2097152);   // (TSEQ+1)*512*2 = 1,049,600

  // sentinel-fill h rows 1..TSEQ (replay-safe: refilled every call)
  k_fill<<<(TSEQ * HIDDEN / 8 + 255) / 256, 256, 0, stream>>>(
      (uint4*)(h_bf + HIDDEN), TSEQ * HIDDEN / 8);
  k_convert<<<2048, 256, 0, stream>>>(Why_w, why_bf, (VOCAB * HIDDEN) / 4);
  k_pre<<<TSEQ, HIDDEN, 0, stream>>>(idx, h0, Wxh_w, Wxh_b, Whh_b, pre, h_bf);
  k_scan<<<NWAVE, 64, 0, stream>>>(pre, Whh_w, h_bf, out + 32768000);
  k_gemm<<<dim3(VOCAB / 128, TSEQ / 128), 256, 0, stream>>>(h_bf + HIDDEN, why_bf, Why_b, out);
}